// Round 7
// baseline (70.322 us; speedup 1.0000x reference)
//
#include <hip/hip_runtime.h>
#include <math.h>

// Problem constants (from setup_inputs: B=16, N=131072, C=2)
#define BATCH 16
#define NPB 131072
#define BLOCKS_PER_B 64
#define THREADS 256
#define PPT (NPB / (BLOCKS_PER_B * THREADS))   // 8 points per thread
#define NACC 27   // 21 (Heff_partial sym) + 6 (g_eff_partial)
#define NPTS ((long)BATCH * NPB)               // 2,097,152 points

// ws layout (floats): partials [B*27*64] | dp_raw [B*6] | sA [NPTS*4] | sB [NPTS*4]
#define WS_PARTIALS_F ((long)BATCH * NACC * BLOCKS_PER_B)
#define WS_DPRAW_F    ((long)BATCH * 6)
#define WS_HEAD_F     (WS_PARTIALS_F + WS_DPRAW_F)
#define WS_NEEDED_B   ((WS_HEAD_F + NPTS * 8) * 4)

__device__ __forceinline__ float safe_lambda(float l) {
    if (isnan(l)) l = 100.0f;
    return fmaxf(l, 0.001f);
}

struct Pt { float4 a0, a1, a2; float2 jd, rv, wv; };

__device__ __forceinline__ void load_pt(const float* __restrict__ Jp, const float* __restrict__ Jd,
                                        const float* __restrict__ r, const float* __restrict__ w,
                                        long n, Pt& P)
{
    const float4* jp4 = (const float4*)(Jp + n * 12);
    P.a0 = jp4[0]; P.a1 = jp4[1]; P.a2 = jp4[2];
    P.jd = *(const float2*)(Jd + n * 2);
    P.rv = *(const float2*)(r  + n * 2);
    P.wv = *(const float2*)(w  + n * 2);
}

// Accumulate Heff_partial = conf*Jp.Jp^T - h*inv*h^T  and  geff_partial = conf*Jp.r - h*inv*gd
// If STORE: also emit per-point m = inv*h (6) and dd0 = inv*gd for the fast depth pass.
template<bool STORE>
__device__ __forceinline__ void acc_pt(const Pt& P, float lam, float (&D)[21], float (&G)[6],
                                       float4* __restrict__ sA, float4* __restrict__ sB, long n)
{
    float jp[12] = {P.a0.x, P.a0.y, P.a0.z, P.a0.w,
                    P.a1.x, P.a1.y, P.a1.z, P.a1.w,
                    P.a2.x, P.a2.y, P.a2.z, P.a2.w};
    const float conf = P.wv.x, nl = P.wv.y;
    const float jdx = P.jd.x, jdy = P.jd.y;
    const float rx  = P.rv.x, ry  = P.rv.y;

    float cjp[12];
#pragma unroll
    for (int i = 0; i < 12; ++i) cjp[i] = conf * jp[i];

    float h[6], hi[6];
#pragma unroll
    for (int p = 0; p < 6; ++p) h[p] = cjp[p] * jdx + cjp[6 + p] * jdy;
    const float Hdd = conf * (jdx * jdx + jdy * jdy);
    const float gd  = conf * (jdx * rx + jdy * ry);
    const float inv = 1.0f / fmaxf(Hdd + lam + nl + 1e-4f, 1e-4f);
#pragma unroll
    for (int p = 0; p < 6; ++p) hi[p] = h[p] * inv;

    if (STORE) {
        sA[n] = make_float4(hi[0], hi[1], hi[2], hi[3]);
        sB[n] = make_float4(hi[4], hi[5], gd * inv, 0.0f);
    }

    int idx = 0;
#pragma unroll
    for (int p = 0; p < 6; ++p) {
#pragma unroll
        for (int q = p; q < 6; ++q) {
            D[idx] += cjp[p] * jp[q];
            D[idx] += cjp[6 + p] * jp[6 + q];
            D[idx] -= hi[p] * h[q];
            ++idx;
        }
    }
#pragma unroll
    for (int p = 0; p < 6; ++p) {
        G[p] += cjp[p] * rx;
        G[p] += cjp[6 + p] * ry;
        G[p] -= hi[p] * gd;
    }
}

// ---------------- Pass 1: per-batch reductions (+ optional intermediate store) ----------------
template<bool STORE>
__global__ __launch_bounds__(THREADS, 2) void dba_pass1(
    const float* __restrict__ r, const float* __restrict__ w,
    const float* __restrict__ Jp, const float* __restrict__ Jd,
    const float* __restrict__ lmbda, float* __restrict__ partials,
    float4* __restrict__ sA, float4* __restrict__ sB)
{
    const int b   = blockIdx.y;
    const int blk = blockIdx.x;
    const int t   = threadIdx.x;
    const float lam = safe_lambda(lmbda[b]);

    float D[21], G[6];
#pragma unroll
    for (int i = 0; i < 21; ++i) D[i] = 0.0f;
#pragma unroll
    for (int i = 0; i < 6; ++i) G[i] = 0.0f;

    const long base = (long)b * NPB + (long)blk * (THREADS * PPT) + t;

    // 2-deep ping-pong software pipeline over PPT=8 points
    Pt A, B;
    load_pt(Jp, Jd, r, w, base + 0 * THREADS, A);
#pragma unroll
    for (int it = 0; it < PPT; it += 2) {
        load_pt(Jp, Jd, r, w, base + (it + 1) * THREADS, B);
        acc_pt<STORE>(A, lam, D, G, sA, sB, base + it * THREADS);
        if (it + 2 < PPT)
            load_pt(Jp, Jd, r, w, base + (it + 2) * THREADS, A);
        acc_pt<STORE>(B, lam, D, G, sA, sB, base + (it + 1) * THREADS);
    }

    // wave-64 butterfly reduce (27 values)
#pragma unroll
    for (int i = 0; i < 21; ++i) {
        float v = D[i];
        v += __shfl_xor(v, 1);  v += __shfl_xor(v, 2);  v += __shfl_xor(v, 4);
        v += __shfl_xor(v, 8);  v += __shfl_xor(v, 16); v += __shfl_xor(v, 32);
        D[i] = v;
    }
#pragma unroll
    for (int i = 0; i < 6; ++i) {
        float v = G[i];
        v += __shfl_xor(v, 1);  v += __shfl_xor(v, 2);  v += __shfl_xor(v, 4);
        v += __shfl_xor(v, 8);  v += __shfl_xor(v, 16); v += __shfl_xor(v, 32);
        G[i] = v;
    }

    // cross-wave reduce via LDS (4 waves)
    __shared__ float s_red[4][NACC];
    const int wid  = t >> 6;
    const int lane = t & 63;
    if (lane == 0) {
#pragma unroll
        for (int i = 0; i < 21; ++i) s_red[wid][i] = D[i];
#pragma unroll
        for (int i = 0; i < 6; ++i)  s_red[wid][21 + i] = G[i];
    }
    __syncthreads();
    if (t < NACC) {
        float v = s_red[0][t] + s_red[1][t] + s_red[2][t] + s_red[3][t];
        // transposed layout: [b][counter][block] -> contiguous rows for the solve
        partials[((long)b * NACC + t) * BLOCKS_PER_B + blk] = v;
    }
}

// ---------------- Pass 2: assemble + 6x6 solve per batch ----------------
__global__ void dba_solve(
    const float* __restrict__ partials, const float* __restrict__ lmbda,
    const int* __restrict__ iter_idx,
    float* __restrict__ out_pose,      // d_out[0:96], clipped
    float* __restrict__ dp_raw)        // ws, unclipped (for pass 3)
{
    const int b = blockIdx.x;
    const int t = threadIdx.x;   // 64 threads
    __shared__ float s[NACC];
    if (t < NACC) {
        const float4* p4 = (const float4*)(partials + ((long)b * NACC + t) * BLOCKS_PER_B);
        float4 a = make_float4(0.f, 0.f, 0.f, 0.f);
#pragma unroll
        for (int k = 0; k < BLOCKS_PER_B / 4; ++k) {
            float4 v = p4[k];
            a.x += v.x; a.y += v.y; a.z += v.z; a.w += v.w;
        }
        s[t] = (a.x + a.y) + (a.z + a.w);
    }
    __syncthreads();
    if (t != 0) return;

    const float lam = safe_lambda(lmbda[b]);
    float H[6][6], g[6];
    int idx = 0;
    for (int p = 0; p < 6; ++p)
        for (int q = p; q < 6; ++q) {
            float v = s[idx];                 // already Hpp - term_to_sub
            H[p][q] = v; H[q][p] = v;
            idx++;
        }
    for (int p = 0; p < 6; ++p) g[p] = s[21 + p];
    for (int p = 0; p < 6; ++p) H[p][p] += lam;

    if (*iter_idx >= 2) {
        for (int p = 3; p < 6; ++p) g[p] = 0.0f;
        for (int p = 3; p < 6; ++p)
            for (int q = 3; q < 6; ++q) H[p][q] += 1e8f;
    }
    for (int p = 0; p < 6; ++p) H[p][p] += 1.0f;
    for (int p = 0; p < 6; ++p) H[p][p] += 0.01f * H[p][p];

    // Gaussian elimination with partial pivoting, augmented column = g
    float A[6][7];
    for (int p = 0; p < 6; ++p) {
        for (int q = 0; q < 6; ++q) A[p][q] = H[p][q];
        A[p][6] = g[p];
    }
    for (int col = 0; col < 6; ++col) {
        int piv = col; float best = fabsf(A[col][col]);
        for (int rr = col + 1; rr < 6; ++rr) {
            float v = fabsf(A[rr][col]);
            if (v > best) { best = v; piv = rr; }
        }
        if (piv != col)
            for (int cc = col; cc < 7; ++cc) {
                float tmp = A[col][cc]; A[col][cc] = A[piv][cc]; A[piv][cc] = tmp;
            }
        const float invp = 1.0f / A[col][col];
        for (int rr = col + 1; rr < 6; ++rr) {
            const float f = A[rr][col] * invp;
            for (int cc = col; cc < 7; ++cc) A[rr][cc] -= f * A[col][cc];
        }
    }
    float x[6];
    for (int rr = 5; rr >= 0; --rr) {
        float v = A[rr][6];
        for (int cc = rr + 1; cc < 6; ++cc) v -= A[rr][cc] * x[cc];
        x[rr] = v / A[rr][rr];
    }
    for (int p = 0; p < 6; ++p) {
        dp_raw[b * 6 + p] = x[p];                       // unclipped, feeds pass 3
        out_pose[b * 6 + p] = fminf(fmaxf(x[p], -2.0f), 2.0f);
    }
}

// ---------------- Pass 3 (fast): delta_depth from stored intermediates ----------------
__global__ __launch_bounds__(THREADS) void dba_pass3_fast(
    const float4* __restrict__ sA, const float4* __restrict__ sB,
    const float* __restrict__ dp_raw, float* __restrict__ out_dd)
{
    const int b   = blockIdx.y;
    const int blk = blockIdx.x;
    const int t   = threadIdx.x;

    float dp[6];
#pragma unroll
    for (int p = 0; p < 6; ++p) dp[p] = dp_raw[b * 6 + p];

    const long base = (long)b * NPB + (long)blk * (THREADS * PPT) + t;

#pragma unroll
    for (int it = 0; it < PPT; ++it) {
        const long n = base + (long)it * THREADS;
        float4 a = sA[n];
        float4 c = sB[n];
        float dd = c.z;                       // dd0 = inv*gd
        dd -= a.x * dp[0];
        dd -= a.y * dp[1];
        dd -= a.z * dp[2];
        dd -= a.w * dp[3];
        dd -= c.x * dp[4];
        dd -= c.y * dp[5];
        out_dd[n] = fminf(fmaxf(dd, -5.0f), 5.0f);
    }
}

// ---------------- Pass 3 (fallback): recompute per point (R3 structure) ----------------
__device__ __forceinline__ float depth_pt(const Pt& P, float lam, const float (&dp)[6])
{
    float jp[12] = {P.a0.x, P.a0.y, P.a0.z, P.a0.w,
                    P.a1.x, P.a1.y, P.a1.z, P.a1.w,
                    P.a2.x, P.a2.y, P.a2.z, P.a2.w};
    const float conf = P.wv.x, nl = P.wv.y;
    const float jdx = P.jd.x, jdy = P.jd.y;
    const float rx  = P.rv.x, ry  = P.rv.y;

    float v = 0.0f;
#pragma unroll
    for (int p = 0; p < 6; ++p) {
        const float h = conf * (jp[p] * jdx + jp[6 + p] * jdy);
        v += h * dp[p];
    }
    const float Hdd = conf * (jdx * jdx + jdy * jdy);
    const float gd  = conf * (jdx * rx + jdy * ry);
    const float inv = 1.0f / fmaxf(Hdd + lam + nl + 1e-4f, 1e-4f);
    float dd = inv * (gd - v);
    return fminf(fmaxf(dd, -5.0f), 5.0f);
}

__global__ __launch_bounds__(THREADS) void dba_pass3(
    const float* __restrict__ r, const float* __restrict__ w,
    const float* __restrict__ Jp, const float* __restrict__ Jd,
    const float* __restrict__ lmbda, const float* __restrict__ dp_raw,
    float* __restrict__ out_dd)
{
    const int b   = blockIdx.y;
    const int blk = blockIdx.x;
    const int t   = threadIdx.x;
    const float lam = safe_lambda(lmbda[b]);

    float dp[6];
#pragma unroll
    for (int p = 0; p < 6; ++p) dp[p] = dp_raw[b * 6 + p];

    const long base = (long)b * NPB + (long)blk * (THREADS * PPT) + t;

    Pt A, B;
    load_pt(Jp, Jd, r, w, base + 0 * THREADS, A);
#pragma unroll
    for (int it = 0; it < PPT; it += 2) {
        load_pt(Jp, Jd, r, w, base + (it + 1) * THREADS, B);
        out_dd[base + it * THREADS] = depth_pt(A, lam, dp);
        if (it + 2 < PPT)
            load_pt(Jp, Jd, r, w, base + (it + 2) * THREADS, A);
        out_dd[base + (it + 1) * THREADS] = depth_pt(B, lam, dp);
    }
}

extern "C" void kernel_launch(void* const* d_in, const int* in_sizes, int n_in,
                              void* d_out, int out_size, void* d_ws, size_t ws_size,
                              hipStream_t stream) {
    const float* r     = (const float*)d_in[0];
    const float* w     = (const float*)d_in[1];
    const float* Jp    = (const float*)d_in[2];
    const float* Jd    = (const float*)d_in[3];
    const float* lmbda = (const float*)d_in[4];
    const int*   iter  = (const int*)  d_in[5];

    float* out      = (float*)d_out;           // [0:96) delta_pose, [96:) delta_depth
    float* partials = (float*)d_ws;
    float* dp_raw   = partials + WS_PARTIALS_F;
    float4* sA      = (float4*)((float*)d_ws + WS_HEAD_F);
    float4* sB      = sA + NPTS;

    const bool store = (ws_size >= (size_t)WS_NEEDED_B);

    dim3 grid(BLOCKS_PER_B, BATCH);
    if (store) {
        dba_pass1<true><<<grid, THREADS, 0, stream>>>(r, w, Jp, Jd, lmbda, partials, sA, sB);
        dba_solve<<<BATCH, 64, 0, stream>>>(partials, lmbda, iter, out, dp_raw);
        dba_pass3_fast<<<grid, THREADS, 0, stream>>>(sA, sB, dp_raw, out + BATCH * 6);
    } else {
        dba_pass1<false><<<grid, THREADS, 0, stream>>>(r, w, Jp, Jd, lmbda, partials, sA, sB);
        dba_solve<<<BATCH, 64, 0, stream>>>(partials, lmbda, iter, out, dp_raw);
        dba_pass3<<<grid, THREADS, 0, stream>>>(r, w, Jp, Jd, lmbda, dp_raw, out + BATCH * 6);
    }
}

// Round 8
// 59.869 us; speedup vs baseline: 1.1746x; 1.1746x over previous
//
#include <hip/hip_runtime.h>
#include <math.h>

// Problem constants (from setup_inputs: B=16, N=131072, C=2)
#define BATCH 16
#define NPB 131072
#define BLOCKS_PER_B 64
#define THREADS 256
#define PPT 8                                  // points per thread
#define PAIRS_PT (PPT / 2)                     // 4 pairs per thread
#define PAIRS_PB (NPB / 2)                     // 65536 pairs per batch
#define PAIRS_PER_BLOCK (THREADS * PAIRS_PT)   // 1024
#define NACC 27   // 21 (Heff_partial sym) + 6 (g_eff_partial)

__device__ __forceinline__ float safe_lambda(float l) {
    if (isnan(l)) l = 100.0f;
    return fmaxf(l, 0.001f);
}

// A pair of consecutive points: 6x float4 of Jp, and float4 each of Jd/r/w (2 pts x 2 ch)
struct Pair {
    float4 j0, j1, j2, j3, j4, j5;
    float4 jd, rv, wv;
};

__device__ __forceinline__ void load_pair(const float* __restrict__ Jp, const float* __restrict__ Jd,
                                          const float* __restrict__ r, const float* __restrict__ w,
                                          long pr, Pair& P)
{
    const float4* jp4 = (const float4*)(Jp + pr * 24);
    P.j0 = jp4[0]; P.j1 = jp4[1]; P.j2 = jp4[2];
    P.j3 = jp4[3]; P.j4 = jp4[4]; P.j5 = jp4[5];
    P.jd = *(const float4*)(Jd + pr * 4);
    P.rv = *(const float4*)(r  + pr * 4);
    P.wv = *(const float4*)(w  + pr * 4);
}

// Accumulate one point given its 12 jp floats and scalars.
__device__ __forceinline__ void acc_one(const float (&jp)[12], float jdx, float jdy,
                                        float rx, float ry, float conf, float nl,
                                        float lam, float (&D)[21], float (&G)[6])
{
    float cjp[12];
#pragma unroll
    for (int i = 0; i < 12; ++i) cjp[i] = conf * jp[i];

    float h[6], hi[6];
#pragma unroll
    for (int p = 0; p < 6; ++p) h[p] = cjp[p] * jdx + cjp[6 + p] * jdy;
    const float Hdd = conf * (jdx * jdx + jdy * jdy);
    const float gd  = conf * (jdx * rx + jdy * ry);
    const float inv = 1.0f / fmaxf(Hdd + lam + nl + 1e-4f, 1e-4f);
#pragma unroll
    for (int p = 0; p < 6; ++p) hi[p] = h[p] * inv;

    int idx = 0;
#pragma unroll
    for (int p = 0; p < 6; ++p) {
#pragma unroll
        for (int q = p; q < 6; ++q) {
            D[idx] += cjp[p] * jp[q];
            D[idx] += cjp[6 + p] * jp[6 + q];
            D[idx] -= hi[p] * h[q];
            ++idx;
        }
    }
#pragma unroll
    for (int p = 0; p < 6; ++p) {
        G[p] += cjp[p] * rx;
        G[p] += cjp[6 + p] * ry;
        G[p] -= hi[p] * gd;
    }
}

__device__ __forceinline__ void acc_pair(const Pair& P, float lam, float (&D)[21], float (&G)[6])
{
    {   // point 0
        float jp[12] = {P.j0.x, P.j0.y, P.j0.z, P.j0.w,
                        P.j1.x, P.j1.y, P.j1.z, P.j1.w,
                        P.j2.x, P.j2.y, P.j2.z, P.j2.w};
        acc_one(jp, P.jd.x, P.jd.y, P.rv.x, P.rv.y, P.wv.x, P.wv.y, lam, D, G);
    }
    {   // point 1
        float jp[12] = {P.j3.x, P.j3.y, P.j3.z, P.j3.w,
                        P.j4.x, P.j4.y, P.j4.z, P.j4.w,
                        P.j5.x, P.j5.y, P.j5.z, P.j5.w};
        acc_one(jp, P.jd.z, P.jd.w, P.rv.z, P.rv.w, P.wv.z, P.wv.w, lam, D, G);
    }
}

// ---------------- Pass 1: per-batch reductions ----------------
__global__ __launch_bounds__(THREADS, 2) void dba_pass1(
    const float* __restrict__ r, const float* __restrict__ w,
    const float* __restrict__ Jp, const float* __restrict__ Jd,
    const float* __restrict__ lmbda, float* __restrict__ partials)
{
    const int b   = blockIdx.y;
    const int blk = blockIdx.x;
    const int t   = threadIdx.x;
    const float lam = safe_lambda(lmbda[b]);

    float D[21], G[6];
#pragma unroll
    for (int i = 0; i < 21; ++i) D[i] = 0.0f;
#pragma unroll
    for (int i = 0; i < 6; ++i) G[i] = 0.0f;

    const long base = (long)b * PAIRS_PB + (long)blk * PAIRS_PER_BLOCK + t;

    // 2-deep ping-pong pipeline over 4 pair-iterations
    Pair A, B;
    load_pair(Jp, Jd, r, w, base + 0 * THREADS, A);
#pragma unroll
    for (int it = 0; it < PAIRS_PT; it += 2) {
        load_pair(Jp, Jd, r, w, base + (it + 1) * THREADS, B);
        acc_pair(A, lam, D, G);
        if (it + 2 < PAIRS_PT)
            load_pair(Jp, Jd, r, w, base + (it + 2) * THREADS, A);
        acc_pair(B, lam, D, G);
    }

    // wave-64 butterfly reduce (27 values)
#pragma unroll
    for (int i = 0; i < 21; ++i) {
        float v = D[i];
        v += __shfl_xor(v, 1);  v += __shfl_xor(v, 2);  v += __shfl_xor(v, 4);
        v += __shfl_xor(v, 8);  v += __shfl_xor(v, 16); v += __shfl_xor(v, 32);
        D[i] = v;
    }
#pragma unroll
    for (int i = 0; i < 6; ++i) {
        float v = G[i];
        v += __shfl_xor(v, 1);  v += __shfl_xor(v, 2);  v += __shfl_xor(v, 4);
        v += __shfl_xor(v, 8);  v += __shfl_xor(v, 16); v += __shfl_xor(v, 32);
        G[i] = v;
    }

    // cross-wave reduce via LDS (4 waves)
    __shared__ float s_red[4][NACC];
    const int wid  = t >> 6;
    const int lane = t & 63;
    if (lane == 0) {
#pragma unroll
        for (int i = 0; i < 21; ++i) s_red[wid][i] = D[i];
#pragma unroll
        for (int i = 0; i < 6; ++i)  s_red[wid][21 + i] = G[i];
    }
    __syncthreads();
    if (t < NACC) {
        float v = s_red[0][t] + s_red[1][t] + s_red[2][t] + s_red[3][t];
        // transposed layout: [b][counter][block] -> contiguous rows for the solve
        partials[((long)b * NACC + t) * BLOCKS_PER_B + blk] = v;
    }
}

// ---------------- Pass 2: assemble + 6x6 solve per batch ----------------
__global__ void dba_solve(
    const float* __restrict__ partials, const float* __restrict__ lmbda,
    const int* __restrict__ iter_idx,
    float* __restrict__ out_pose,      // d_out[0:96], clipped
    float* __restrict__ dp_raw)        // ws, unclipped (for pass 3)
{
    const int b = blockIdx.x;
    const int t = threadIdx.x;   // 64 threads
    __shared__ float s[NACC];
    if (t < NACC) {
        const float4* p4 = (const float4*)(partials + ((long)b * NACC + t) * BLOCKS_PER_B);
        float4 a = make_float4(0.f, 0.f, 0.f, 0.f);
#pragma unroll
        for (int k = 0; k < BLOCKS_PER_B / 4; ++k) {
            float4 v = p4[k];
            a.x += v.x; a.y += v.y; a.z += v.z; a.w += v.w;
        }
        s[t] = (a.x + a.y) + (a.z + a.w);
    }
    __syncthreads();
    if (t != 0) return;

    const float lam = safe_lambda(lmbda[b]);
    float H[6][6], g[6];
    int idx = 0;
    for (int p = 0; p < 6; ++p)
        for (int q = p; q < 6; ++q) {
            float v = s[idx];                 // already Hpp - term_to_sub
            H[p][q] = v; H[q][p] = v;
            idx++;
        }
    for (int p = 0; p < 6; ++p) g[p] = s[21 + p];
    for (int p = 0; p < 6; ++p) H[p][p] += lam;

    if (*iter_idx >= 2) {
        for (int p = 3; p < 6; ++p) g[p] = 0.0f;
        for (int p = 3; p < 6; ++p)
            for (int q = 3; q < 6; ++q) H[p][q] += 1e8f;
    }
    for (int p = 0; p < 6; ++p) H[p][p] += 1.0f;
    for (int p = 0; p < 6; ++p) H[p][p] += 0.01f * H[p][p];

    // Gaussian elimination with partial pivoting, augmented column = g
    float A[6][7];
    for (int p = 0; p < 6; ++p) {
        for (int q = 0; q < 6; ++q) A[p][q] = H[p][q];
        A[p][6] = g[p];
    }
    for (int col = 0; col < 6; ++col) {
        int piv = col; float best = fabsf(A[col][col]);
        for (int rr = col + 1; rr < 6; ++rr) {
            float v = fabsf(A[rr][col]);
            if (v > best) { best = v; piv = rr; }
        }
        if (piv != col)
            for (int cc = col; cc < 7; ++cc) {
                float tmp = A[col][cc]; A[col][cc] = A[piv][cc]; A[piv][cc] = tmp;
            }
        const float invp = 1.0f / A[col][col];
        for (int rr = col + 1; rr < 6; ++rr) {
            const float f = A[rr][col] * invp;
            for (int cc = col; cc < 7; ++cc) A[rr][cc] -= f * A[col][cc];
        }
    }
    float x[6];
    for (int rr = 5; rr >= 0; --rr) {
        float v = A[rr][6];
        for (int cc = rr + 1; cc < 6; ++cc) v -= A[rr][cc] * x[cc];
        x[rr] = v / A[rr][rr];
    }
    for (int p = 0; p < 6; ++p) {
        dp_raw[b * 6 + p] = x[p];                       // unclipped, feeds pass 3
        out_pose[b * 6 + p] = fminf(fmaxf(x[p], -2.0f), 2.0f);
    }
}

// ---------------- Pass 3: delta_depth per point (pair-packed) ----------------
__device__ __forceinline__ float depth_one(const float (&jp)[12], float jdx, float jdy,
                                           float rx, float ry, float conf, float nl,
                                           float lam, const float (&dp)[6])
{
    float v = 0.0f;
#pragma unroll
    for (int p = 0; p < 6; ++p) {
        const float h = conf * (jp[p] * jdx + jp[6 + p] * jdy);
        v += h * dp[p];
    }
    const float Hdd = conf * (jdx * jdx + jdy * jdy);
    const float gd  = conf * (jdx * rx + jdy * ry);
    const float inv = 1.0f / fmaxf(Hdd + lam + nl + 1e-4f, 1e-4f);
    float dd = inv * (gd - v);
    return fminf(fmaxf(dd, -5.0f), 5.0f);
}

__device__ __forceinline__ float2 depth_pair(const Pair& P, float lam, const float (&dp)[6])
{
    float2 out;
    {
        float jp[12] = {P.j0.x, P.j0.y, P.j0.z, P.j0.w,
                        P.j1.x, P.j1.y, P.j1.z, P.j1.w,
                        P.j2.x, P.j2.y, P.j2.z, P.j2.w};
        out.x = depth_one(jp, P.jd.x, P.jd.y, P.rv.x, P.rv.y, P.wv.x, P.wv.y, lam, dp);
    }
    {
        float jp[12] = {P.j3.x, P.j3.y, P.j3.z, P.j3.w,
                        P.j4.x, P.j4.y, P.j4.z, P.j4.w,
                        P.j5.x, P.j5.y, P.j5.z, P.j5.w};
        out.y = depth_one(jp, P.jd.z, P.jd.w, P.rv.z, P.rv.w, P.wv.z, P.wv.w, lam, dp);
    }
    return out;
}

__global__ __launch_bounds__(THREADS) void dba_pass3(
    const float* __restrict__ r, const float* __restrict__ w,
    const float* __restrict__ Jp, const float* __restrict__ Jd,
    const float* __restrict__ lmbda, const float* __restrict__ dp_raw,
    float* __restrict__ out_dd)
{
    const int b   = blockIdx.y;
    const int blk = blockIdx.x;
    const int t   = threadIdx.x;
    const float lam = safe_lambda(lmbda[b]);

    float dp[6];
#pragma unroll
    for (int p = 0; p < 6; ++p) dp[p] = dp_raw[b * 6 + p];

    const long base = (long)b * PAIRS_PB + (long)blk * PAIRS_PER_BLOCK + t;

    Pair A, B;
    load_pair(Jp, Jd, r, w, base + 0 * THREADS, A);
#pragma unroll
    for (int it = 0; it < PAIRS_PT; it += 2) {
        load_pair(Jp, Jd, r, w, base + (it + 1) * THREADS, B);
        *(float2*)(out_dd + (base + it * THREADS) * 2) = depth_pair(A, lam, dp);
        if (it + 2 < PAIRS_PT)
            load_pair(Jp, Jd, r, w, base + (it + 2) * THREADS, A);
        *(float2*)(out_dd + (base + (it + 1) * THREADS) * 2) = depth_pair(B, lam, dp);
    }
}

extern "C" void kernel_launch(void* const* d_in, const int* in_sizes, int n_in,
                              void* d_out, int out_size, void* d_ws, size_t ws_size,
                              hipStream_t stream) {
    const float* r     = (const float*)d_in[0];
    const float* w     = (const float*)d_in[1];
    const float* Jp    = (const float*)d_in[2];
    const float* Jd    = (const float*)d_in[3];
    const float* lmbda = (const float*)d_in[4];
    const int*   iter  = (const int*)  d_in[5];

    float* out      = (float*)d_out;           // [0:96) delta_pose, [96:) delta_depth
    float* partials = (float*)d_ws;            // BATCH * NACC * BLOCKS_PER_B floats
    float* dp_raw   = partials + (long)BATCH * NACC * BLOCKS_PER_B;  // BATCH*6 floats

    dim3 grid(BLOCKS_PER_B, BATCH);
    dba_pass1<<<grid, THREADS, 0, stream>>>(r, w, Jp, Jd, lmbda, partials);
    dba_solve<<<BATCH, 64, 0, stream>>>(partials, lmbda, iter, out, dp_raw);
    dba_pass3<<<grid, THREADS, 0, stream>>>(r, w, Jp, Jd, lmbda, dp_raw, out + BATCH * 6);
}